// Round 4
// baseline (566.882 us; speedup 1.0000x reference)
//
#include <hip/hip_runtime.h>
#include <hip/hip_bf16.h>
#include <math.h>

#define B_   32
#define T_   4096
#define D_   1024
#define H_   256
#define KTH  2048           // threshold_index = int(T*0.5)
#define NC   16
#define TC   (T_/NC)
#define EPSB 4.0e-3f        // refinement band half-width (~8 sigma of bf16 e-error)
#define MAXBAND 256
#define RB   4              // refine rows per block-group

typedef __attribute__((ext_vector_type(8))) short short8;
typedef __attribute__((ext_vector_type(4))) float f32x4;

// ---------- helpers ----------
__device__ inline unsigned f2s(float f) {
    unsigned u = __float_as_uint(f);
    return (u & 0x80000000u) ? ~u : (u | 0x80000000u);
}
__device__ inline float s2f(unsigned s) {
    unsigned x = (s & 0x80000000u) ? (s & 0x7fffffffu) : ~s;
    return __uint_as_float(x);
}
__device__ inline unsigned f2bf_rne(float f) {      // round-to-nearest-even bf16
    unsigned u = __float_as_uint(f);
    return (u + 0x7FFFu + ((u >> 16) & 1u)) >> 16;
}
__device__ inline unsigned pk2(float a, float b) {
    return f2bf_rne(a) | (f2bf_rne(b) << 16);
}
__device__ inline int block_sum_i(int v, int* sb, int tid) {
    #pragma unroll
    for (int o = 32; o; o >>= 1) v += __shfl_down(v, o);
    __syncthreads();
    if ((tid & 63) == 0) sb[tid >> 6] = v;
    __syncthreads();
    return sb[0] + sb[1] + sb[2] + sb[3];
}
__device__ inline float block_max_f(float v, float* sb, int tid) {
    #pragma unroll
    for (int o = 32; o; o >>= 1) v = fmaxf(v, __shfl_down(v, o));
    __syncthreads();
    if ((tid & 63) == 0) sb[tid >> 6] = v;
    __syncthreads();
    return fmaxf(fmaxf(sb[0], sb[1]), fmaxf(sb[2], sb[3]));
}
__device__ inline float block_sum_f(float v, float* sb, int tid) {
    #pragma unroll
    for (int o = 32; o; o >>= 1) v += __shfl_down(v, o);
    __syncthreads();
    if ((tid & 63) == 0) sb[tid >> 6] = v;
    __syncthreads();
    return sb[0] + sb[1] + sb[2] + sb[3];
}

// ---------- W1 [K][N] fp32 -> W1T bf16(RNE) [N][K] ----------
__global__ __launch_bounds__(256) void k_w1t(const float* __restrict__ W1,
                                             ushort* __restrict__ Whi) {
    __shared__ float tile[32][33];
    const int kb = blockIdx.x * 32, nb = blockIdx.y * 32;
    const int tx = threadIdx.x & 31, ty = threadIdx.x >> 5;   // ty 0..7
    #pragma unroll
    for (int i = 0; i < 4; i++)
        tile[ty + 8*i][tx] = W1[(long)(kb + ty + 8*i) * H_ + nb + tx];
    __syncthreads();
    #pragma unroll
    for (int i = 0; i < 4; i++) {
        long o = (long)(nb + ty + 8*i) * D_ + kb + tx;
        Whi[o] = (ushort)f2bf_rne(tile[tx][ty + 8*i]);
    }
}

// ---------- phase 1: LDS-free direct-to-register MFMA GEMM + tanh/W2 epilogue ----------
// Block = 256 thr = 4 waves (1m x 4n). Block tile 64 rows x 256 cols.
// Each wave: 64 rows x 64 cols = 4x4 frags of 16x16x32, A and B fragments
// loaded straight from global (A: 32B/lane from x; B: 16B/lane from L2-resident Whi).
__global__ __launch_bounds__(256) void k_e_mfma(
    const float* __restrict__ x,
    const ushort* __restrict__ Whi,
    const float* __restrict__ b1, const float* __restrict__ W2,
    const float* __restrict__ b2, float* __restrict__ e_out)
{
    __shared__ float sRed[4][64];

    const int tid  = threadIdx.x;
    const int lane = tid & 63;
    const int wn   = tid >> 6;              // col panel 0..3
    const int l15  = lane & 15, lg = lane >> 4;
    const long row0 = (long)blockIdx.x * 64;

    // A frag fm: lane reads x[row0 + fm*16 + l15, k0 + lg*8 .. +7]  (8 fp32, 32B)
    const float* aptr[4];
    #pragma unroll
    for (int fm = 0; fm < 4; fm++)
        aptr[fm] = x + (row0 + fm * 16 + l15) * (long)D_ + lg * 8;
    // B frag fn: lane reads Whi[wn*64 + fn*16 + l15, k0 + lg*8 .. +7] (8 bf16, 16B)
    const ushort* bptr[4];
    #pragma unroll
    for (int fn = 0; fn < 4; fn++)
        bptr[fn] = Whi + (long)(wn * 64 + fn * 16 + l15) * D_ + lg * 8;

    f32x4 acc[4][4];
    #pragma unroll
    for (int i = 0; i < 4; i++)
        #pragma unroll
        for (int j = 0; j < 4; j++) acc[i][j] = (f32x4){0.f, 0.f, 0.f, 0.f};

    #pragma unroll 2
    for (int k0 = 0; k0 < D_; k0 += 32) {
        short8 av[4], bv[4];
        #pragma unroll
        for (int fm = 0; fm < 4; fm++) {
            float4 u = *(const float4*)(aptr[fm] + k0);
            float4 v = *(const float4*)(aptr[fm] + k0 + 4);
            union { uint4 u4; short8 s8; } cv;
            cv.u4 = make_uint4(pk2(u.x, u.y), pk2(u.z, u.w),
                               pk2(v.x, v.y), pk2(v.z, v.w));
            av[fm] = cv.s8;
        }
        #pragma unroll
        for (int fn = 0; fn < 4; fn++)
            bv[fn] = *(const short8*)(bptr[fn] + k0);
        #pragma unroll
        for (int fm = 0; fm < 4; fm++)
            #pragma unroll
            for (int fn = 0; fn < 4; fn++)
                acc[fm][fn] = __builtin_amdgcn_mfma_f32_16x16x32_bf16(av[fm], bv[fn], acc[fm][fn], 0, 0, 0);
    }

    // epilogue: e partial = sum_j tanh(G+b1[j])*W2[j]; D frag: col=l15, row=lg*4+r
    float b1v[4], w2v[4];
    #pragma unroll
    for (int fn = 0; fn < 4; fn++) {
        int j = wn * 64 + fn * 16 + l15;
        b1v[fn] = b1[j]; w2v[fn] = W2[j];
    }
    #pragma unroll
    for (int fm = 0; fm < 4; fm++) {
        #pragma unroll
        for (int r = 0; r < 4; r++) {
            float s = 0.f;
            #pragma unroll
            for (int fn = 0; fn < 4; fn++)
                s += tanhf(acc[fm][fn][r] + b1v[fn]) * w2v[fn];
            s += __shfl_xor(s, 1); s += __shfl_xor(s, 2);
            s += __shfl_xor(s, 4); s += __shfl_xor(s, 8);
            if (l15 == 0) sRed[wn][fm * 16 + lg * 4 + r] = s;
        }
    }
    __syncthreads();
    if (tid < 64)
        e_out[row0 + tid] = sRed[0][tid] + sRed[1][tid] + sRed[2][tid] + sRed[3][tid] + b2[0];
}

// ---------- phase 2: rank threshold; BUILD=1 -> band list, BUILD=0 -> softmax ----------
template<int BUILD>
__global__ __launch_bounds__(256) void k_thresh(const float* __restrict__ e,
                                                float* __restrict__ beta,
                                                int* __restrict__ counts,
                                                int* __restrict__ list) {
    __shared__ int   sbi[4];
    __shared__ float sbf[4];
    __shared__ int   scnt;
    const int b = blockIdx.x, tid = threadIdx.x;
    const float* eb = e + (long)b * T_;

    float fe[16]; unsigned ue[16];
    #pragma unroll
    for (int i = 0; i < 16; i++) { fe[i] = eb[tid + i * 256]; ue[i] = f2s(fe[i]); }

    unsigned lo = 0u, hi = 0xFFFFFFFFu;
    while (lo < hi) {
        unsigned mid = lo + ((hi - lo) >> 1);
        int c = 0;
        #pragma unroll
        for (int i = 0; i < 16; i++) c += (ue[i] <= mid) ? 1 : 0;
        int total = block_sum_i(c, sbi, tid);
        if (total >= KTH + 1) hi = mid; else lo = mid + 1;
    }
    const float thr = s2f(lo);

    if (BUILD) {
        if (tid == 0) scnt = 0;
        __syncthreads();
        #pragma unroll
        for (int i = 0; i < 16; i++) {
            if (fabsf(fe[i] - thr) <= EPSB) {
                int p = atomicAdd(&scnt, 1);
                if (p < MAXBAND) list[b * MAXBAND + p] = tid + i * 256;
            }
        }
        __syncthreads();
        if (tid == 0) counts[b] = scnt < MAXBAND ? scnt : MAXBAND;
    } else {
        float m = -INFINITY;
        #pragma unroll
        for (int i = 0; i < 16; i++) if (fe[i] < thr) m = fmaxf(m, fe[i]);
        m = block_max_f(m, sbf, tid);
        float s = 0.f;
        #pragma unroll
        for (int i = 0; i < 16; i++) if (fe[i] < thr) s += expf(fe[i] - m);
        s = block_sum_f(s, sbf, tid);
        const float inv = 1.0f / s;
        #pragma unroll
        for (int i = 0; i < 16; i++)
            beta[(long)b * T_ + tid + i * 256] = (fe[i] < thr) ? expf(fe[i] - m) * inv : 0.0f;
    }
}

// ---------- phase 2.5: exact fp32 recompute of band rows, RB rows share one W1 stream ----------
__global__ __launch_bounds__(256) void k_refine(const float* __restrict__ x,
        const float* __restrict__ W1, const float* __restrict__ b1,
        const float* __restrict__ W2, const float* __restrict__ b2,
        const int* __restrict__ counts, const int* __restrict__ list,
        float* __restrict__ e) {
    const int b   = blockIdx.y;
    const int blk = blockIdx.x;            // 0..15
    const int cnt = counts[b];
    const int tid = threadIdx.x;
    __shared__ float xs[RB][D_];           // 16 KB
    __shared__ float sbf[4];

    for (int g = blk * RB; g < cnt; g += 16 * RB) {
        const int nr = min(RB, cnt - g);
        // stage the group's x rows
        for (int j = 0; j < nr; j++) {
            const int t = list[b * MAXBAND + g + j];
            *(float4*)&xs[j][tid * 4] =
                *(const float4*)&x[((long)b * T_ + t) * D_ + tid * 4];
        }
        __syncthreads();

        float a0 = 0.f, a1 = 0.f, a2 = 0.f, a3 = 0.f;
        for (int k0 = 0; k0 < D_; k0 += 4) {
            const float w0 = W1[(long)(k0 + 0) * H_ + tid];
            const float w1v = W1[(long)(k0 + 1) * H_ + tid];
            const float w2q = W1[(long)(k0 + 2) * H_ + tid];
            const float w3 = W1[(long)(k0 + 3) * H_ + tid];
            {
                float4 xv = *(const float4*)&xs[0][k0];
                a0 = fmaf(xv.x, w0, a0); a0 = fmaf(xv.y, w1v, a0);
                a0 = fmaf(xv.z, w2q, a0); a0 = fmaf(xv.w, w3, a0);
            }
            {
                float4 xv = *(const float4*)&xs[1][k0];
                a1 = fmaf(xv.x, w0, a1); a1 = fmaf(xv.y, w1v, a1);
                a1 = fmaf(xv.z, w2q, a1); a1 = fmaf(xv.w, w3, a1);
            }
            {
                float4 xv = *(const float4*)&xs[2][k0];
                a2 = fmaf(xv.x, w0, a2); a2 = fmaf(xv.y, w1v, a2);
                a2 = fmaf(xv.z, w2q, a2); a2 = fmaf(xv.w, w3, a2);
            }
            {
                float4 xv = *(const float4*)&xs[3][k0];
                a3 = fmaf(xv.x, w0, a3); a3 = fmaf(xv.y, w1v, a3);
                a3 = fmaf(xv.z, w2q, a3); a3 = fmaf(xv.w, w3, a3);
            }
        }

        float aj[RB] = {a0, a1, a2, a3};
        for (int j = 0; j < nr; j++) {
            float v = tanhf(aj[j] + b1[tid]) * W2[tid];
            float tot = block_sum_f(v, sbf, tid);
            if (tid == 0) {
                const int t = list[b * MAXBAND + g + j];
                e[(long)b * T_ + t] = tot + b2[0];
            }
            __syncthreads();
        }
        __syncthreads();
    }
}

// ---------- phase 3: partial[b][c][d] = sum_{t in chunk} beta*x ----------
__global__ __launch_bounds__(256) void k_pv(const float* __restrict__ x,
                                            const float* __restrict__ beta,
                                            float* __restrict__ partial) {
    const int c = blockIdx.x, b = blockIdx.y, tid = threadIdx.x;
    __shared__ float sBeta[TC];
    sBeta[tid] = beta[(long)b * T_ + c * TC + tid];
    __syncthreads();
    float4 acc = {0.f, 0.f, 0.f, 0.f};
    const float* xb = x + ((long)b * T_ + (long)c * TC) * D_ + tid * 4;
    for (int t = 0; t < TC; t++) {
        float w = sBeta[t];
        if (w != 0.0f) {
            float4 v = *reinterpret_cast<const float4*>(xb + (long)t * D_);
            acc.x = fmaf(w, v.x, acc.x);
            acc.y = fmaf(w, v.y, acc.y);
            acc.z = fmaf(w, v.z, acc.z);
            acc.w = fmaf(w, v.w, acc.w);
        }
    }
    *reinterpret_cast<float4*>(&partial[(((long)b * NC) + c) * D_ + tid * 4]) = acc;
}

// ---------- phase 4 ----------
__global__ __launch_bounds__(256) void k_red(const float* __restrict__ partial,
                                             float* __restrict__ out) {
    const int b = blockIdx.x, tid = threadIdx.x;
    float4 acc = {0.f, 0.f, 0.f, 0.f};
    #pragma unroll
    for (int c = 0; c < NC; c++) {
        float4 v = *reinterpret_cast<const float4*>(&partial[(((long)b * NC) + c) * D_ + tid * 4]);
        acc.x += v.x; acc.y += v.y; acc.z += v.z; acc.w += v.w;
    }
    *reinterpret_cast<float4*>(&out[(long)b * D_ + tid * 4]) = acc;
}

extern "C" void kernel_launch(void* const* d_in, const int* in_sizes, int n_in,
                              void* d_out, int out_size, void* d_ws, size_t ws_size,
                              hipStream_t stream) {
    const float* x  = (const float*)d_in[0];
    const float* W1 = (const float*)d_in[1];
    const float* b1 = (const float*)d_in[2];
    const float* W2 = (const float*)d_in[3];
    const float* b2 = (const float*)d_in[4];
    float* out = (float*)d_out;

    char* ws = (char*)d_ws;
    float* e       = (float*)ws;  ws += (size_t)B_ * T_ * 4;
    float* beta    = (float*)ws;  ws += (size_t)B_ * T_ * 4;
    float* partial = (float*)ws;  ws += (size_t)B_ * NC * D_ * 4;
    ushort* Whi    = (ushort*)ws; ws += (size_t)H_ * D_ * 2;
    int* counts    = (int*)ws;    ws += 128;
    int* list      = (int*)ws;

    k_w1t<<<dim3(D_ / 32, H_ / 32), 256, 0, stream>>>(W1, Whi);
    k_e_mfma<<<(B_ * T_) / 64, 256, 0, stream>>>(x, Whi, b1, W2, b2, e);
    k_thresh<1><<<B_, 256, 0, stream>>>(e, nullptr, counts, list);
    k_refine<<<dim3(16, B_), 256, 0, stream>>>(x, W1, b1, W2, b2, counts, list, e);
    k_thresh<0><<<B_, 256, 0, stream>>>(e, beta, counts, list);
    k_pv<<<dim3(NC, B_), 256, 0, stream>>>(x, beta, partial);
    k_red<<<B_, 256, 0, stream>>>(partial, out);
}

// Round 5
// 353.285 us; speedup vs baseline: 1.6046x; 1.6046x over previous
//
#include <hip/hip_runtime.h>
#include <hip/hip_bf16.h>
#include <math.h>

#define B_   32
#define T_   4096
#define D_   1024
#define H_   256
#define KTH  2048           // threshold_index = int(T*0.5)
#define NC   16
#define TC   (T_/NC)
#define BM   128
#define BKE  32
#define NTE  (D_/BKE)       // 32 k-steps
#define EPSB 4.0e-3f        // refinement band half-width (~8 sigma of bf16 e-error)
#define MAXBAND 256
#define RB   4              // refine rows per block-group

typedef __attribute__((ext_vector_type(8))) short short8;
typedef __attribute__((ext_vector_type(4))) float f32x4;

// ---------- helpers ----------
__device__ inline unsigned f2s(float f) {
    unsigned u = __float_as_uint(f);
    return (u & 0x80000000u) ? ~u : (u | 0x80000000u);
}
__device__ inline float s2f(unsigned s) {
    unsigned x = (s & 0x80000000u) ? (s & 0x7fffffffu) : ~s;
    return __uint_as_float(x);
}
__device__ inline unsigned f2bf_rne(float f) {      // round-to-nearest-even bf16
    unsigned u = __float_as_uint(f);
    return (u + 0x7FFFu + ((u >> 16) & 1u)) >> 16;
}
__device__ inline unsigned pk2(float a, float b) {
    return f2bf_rne(a) | (f2bf_rne(b) << 16);
}
__device__ inline int block_sum_i(int v, int* sb, int tid) {
    #pragma unroll
    for (int o = 32; o; o >>= 1) v += __shfl_down(v, o);
    __syncthreads();
    if ((tid & 63) == 0) sb[tid >> 6] = v;
    __syncthreads();
    return sb[0] + sb[1] + sb[2] + sb[3];
}
__device__ inline float block_max_f(float v, float* sb, int tid) {
    #pragma unroll
    for (int o = 32; o; o >>= 1) v = fmaxf(v, __shfl_down(v, o));
    __syncthreads();
    if ((tid & 63) == 0) sb[tid >> 6] = v;
    __syncthreads();
    return fmaxf(fmaxf(sb[0], sb[1]), fmaxf(sb[2], sb[3]));
}
__device__ inline float block_sum_f(float v, float* sb, int tid) {
    #pragma unroll
    for (int o = 32; o; o >>= 1) v += __shfl_down(v, o);
    __syncthreads();
    if ((tid & 63) == 0) sb[tid >> 6] = v;
    __syncthreads();
    return sb[0] + sb[1] + sb[2] + sb[3];
}

// ---------- W1 [K][N] fp32 -> W1T bf16(RNE) [N][K] ----------
__global__ __launch_bounds__(256) void k_w1t(const float* __restrict__ W1,
                                             ushort* __restrict__ Whi) {
    __shared__ float tile[32][33];
    const int kb = blockIdx.x * 32, nb = blockIdx.y * 32;
    const int tx = threadIdx.x & 31, ty = threadIdx.x >> 5;   // ty 0..7
    #pragma unroll
    for (int i = 0; i < 4; i++)
        tile[ty + 8*i][tx] = W1[(long)(kb + ty + 8*i) * H_ + nb + tx];
    __syncthreads();
    #pragma unroll
    for (int i = 0; i < 4; i++) {
        long o = (long)(nb + ty + 8*i) * D_ + kb + tx;
        Whi[o] = (ushort)f2bf_rne(tile[tx][ty + 8*i]);
    }
}

// ---------- phase 1: staged MFMA GEMM + tanh/W2 epilogue -> e ----------
// 512 thr = 8 waves (2m x 4n), block tile 128x256, BK=32, double-buffered LDS.
// LDS layout (both tiles, bf16): [slab=row>>4][kchunk=0..3][row&15][8] so a
// fragment ds_read_b128 is addr = base + lane*16 (conflict-free by layout).
// A: reg-staged (load early / cvt+ds_write late). B: global_load_lds width=16
// with permuted per-lane global source.
__global__ __launch_bounds__(512, 4) void k_e_mfma(
    const float* __restrict__ x,
    const ushort* __restrict__ Whi,
    const float* __restrict__ b1, const float* __restrict__ W2,
    const float* __restrict__ b2, float* __restrict__ e_out)
{
    __shared__ ushort sA[2][BM * BKE];   // 8 KB per buf
    __shared__ ushort sB[2][H_ * BKE];   // 16 KB per buf
    __shared__ float  sRed[4][BM];

    const int tid  = threadIdx.x;
    const int lane = tid & 63;
    const int wv   = tid >> 6;
    const int wm   = wv >> 2, wn = wv & 3;
    const int l15  = lane & 15, lg = lane >> 4;
    const long row0 = (long)blockIdx.x * BM;

    // ----- A staging map: thread -> (row=tid>>2, kchunk j=tid&3), 8 fp32 (32B)
    const int ar = tid >> 2, aj = tid & 3;
    const float* aga = x + (row0 + ar) * (long)D_ + aj * 8;
    // LDS dst (ushort idx): slab=ar>>4, chunk=aj, nlow=ar&15
    const int awo = (ar >> 4) * 512 + aj * 128 + (ar & 15) * 8;

    // ----- B staging map: two 16B chunks per thread, linear chunk idx c=tid+l*512
    // chunk c holds: n=(c>>6)*16+(c&15), kchunk=(c>>4)&3
    int  bn[2], bk[2], bdst[2];
    #pragma unroll
    for (int l = 0; l < 2; l++) {
        const int c = tid + l * 512;
        bn[l]   = (c >> 6) * 16 + (c & 15);
        bk[l]   = (c >> 4) & 3;
        bdst[l] = c * 8;                      // ushort idx = c*16B
    }
    const ushort* bga0 = Whi + (long)bn[0] * D_ + bk[0] * 8;
    const ushort* bga1 = Whi + (long)bn[1] * D_ + bk[1] * 8;

    // ----- fragment read offsets (lane-linear by construction)
    int aoff[4], boff[4];
    #pragma unroll
    for (int fm = 0; fm < 4; fm++) {
        const int slab = wm * 4 + fm;         // row = wm*64+fm*16+l15
        aoff[fm] = slab * 512 + lg * 128 + l15 * 8;
    }
    #pragma unroll
    for (int fn = 0; fn < 4; fn++) {
        const int slab = wn * 4 + fn;         // n = wn*64+fn*16+l15
        boff[fn] = slab * 512 + lg * 128 + l15 * 8;
    }

    f32x4 acc[4][4];
    #pragma unroll
    for (int i = 0; i < 4; i++)
        #pragma unroll
        for (int j = 0; j < 4; j++) acc[i][j] = (f32x4){0.f, 0.f, 0.f, 0.f};

    // ----- prologue: stage k-step 0 into buf 0
    {
        float4 a0 = *(const float4*)(aga);
        float4 a1 = *(const float4*)(aga + 4);
        __builtin_amdgcn_global_load_lds(
            (const __attribute__((address_space(1))) unsigned int*)(bga0),
            (__attribute__((address_space(3))) unsigned int*)&sB[0][bdst[0]], 16, 0, 0);
        __builtin_amdgcn_global_load_lds(
            (const __attribute__((address_space(1))) unsigned int*)(bga1),
            (__attribute__((address_space(3))) unsigned int*)&sB[0][bdst[1]], 16, 0, 0);
        uint4 ap = make_uint4(pk2(a0.x, a0.y), pk2(a0.z, a0.w),
                              pk2(a1.x, a1.y), pk2(a1.z, a1.w));
        *(uint4*)&sA[0][awo] = ap;
    }
    __syncthreads();

    int cur = 0;
    for (int t = 0; t < NTE - 1; ++t) {
        const int ko = (t + 1) * BKE;
        // issue next-tile loads first (latency hides under MFMA below)
        float4 a0 = *(const float4*)(aga + ko);
        float4 a1 = *(const float4*)(aga + ko + 4);
        __builtin_amdgcn_global_load_lds(
            (const __attribute__((address_space(1))) unsigned int*)(bga0 + ko),
            (__attribute__((address_space(3))) unsigned int*)&sB[cur ^ 1][bdst[0]], 16, 0, 0);
        __builtin_amdgcn_global_load_lds(
            (const __attribute__((address_space(1))) unsigned int*)(bga1 + ko),
            (__attribute__((address_space(3))) unsigned int*)&sB[cur ^ 1][bdst[1]], 16, 0, 0);

        // compute current tile
        short8 bfr[4];
        #pragma unroll
        for (int fn = 0; fn < 4; fn++)
            bfr[fn] = *(const short8*)&sB[cur][boff[fn]];
        #pragma unroll
        for (int fm = 0; fm < 4; fm++) {
            short8 afr = *(const short8*)&sA[cur][aoff[fm]];
            #pragma unroll
            for (int fn = 0; fn < 4; fn++)
                acc[fm][fn] = __builtin_amdgcn_mfma_f32_16x16x32_bf16(afr, bfr[fn], acc[fm][fn], 0, 0, 0);
        }

        // write next A tile (cvt fp32->bf16) after compute
        uint4 ap = make_uint4(pk2(a0.x, a0.y), pk2(a0.z, a0.w),
                              pk2(a1.x, a1.y), pk2(a1.z, a1.w));
        *(uint4*)&sA[cur ^ 1][awo] = ap;

        __syncthreads();   // drains vmcnt (B lds-loads landed) + syncs buffers
        cur ^= 1;
    }
    // final tile
    {
        short8 bfr[4];
        #pragma unroll
        for (int fn = 0; fn < 4; fn++)
            bfr[fn] = *(const short8*)&sB[cur][boff[fn]];
        #pragma unroll
        for (int fm = 0; fm < 4; fm++) {
            short8 afr = *(const short8*)&sA[cur][aoff[fm]];
            #pragma unroll
            for (int fn = 0; fn < 4; fn++)
                acc[fm][fn] = __builtin_amdgcn_mfma_f32_16x16x32_bf16(afr, bfr[fn], acc[fm][fn], 0, 0, 0);
        }
    }

    // epilogue: e partial = sum_j tanh(G+b1[j])*W2[j]; D frag: col=l15, row=lg*4+r
    float b1v[4], w2v[4];
    #pragma unroll
    for (int fn = 0; fn < 4; fn++) {
        int j = wn * 64 + fn * 16 + l15;
        b1v[fn] = b1[j]; w2v[fn] = W2[j];
    }
    #pragma unroll
    for (int fm = 0; fm < 4; fm++) {
        #pragma unroll
        for (int r = 0; r < 4; r++) {
            float s = 0.f;
            #pragma unroll
            for (int fn = 0; fn < 4; fn++)
                s += tanhf(acc[fm][fn][r] + b1v[fn]) * w2v[fn];
            s += __shfl_xor(s, 1); s += __shfl_xor(s, 2);
            s += __shfl_xor(s, 4); s += __shfl_xor(s, 8);
            if (l15 == 0) sRed[wn][wm * 64 + fm * 16 + lg * 4 + r] = s;
        }
    }
    __syncthreads();
    if (tid < BM)
        e_out[row0 + tid] = sRed[0][tid] + sRed[1][tid] + sRed[2][tid] + sRed[3][tid] + b2[0];
}

// ---------- phase 2: rank threshold; BUILD=1 -> band list, BUILD=0 -> softmax ----------
template<int BUILD>
__global__ __launch_bounds__(256) void k_thresh(const float* __restrict__ e,
                                                float* __restrict__ beta,
                                                int* __restrict__ counts,
                                                int* __restrict__ list) {
    __shared__ int   sbi[4];
    __shared__ float sbf[4];
    __shared__ int   scnt;
    const int b = blockIdx.x, tid = threadIdx.x;
    const float* eb = e + (long)b * T_;

    float fe[16]; unsigned ue[16];
    #pragma unroll
    for (int i = 0; i < 16; i++) { fe[i] = eb[tid + i * 256]; ue[i] = f2s(fe[i]); }

    unsigned lo = 0u, hi = 0xFFFFFFFFu;
    while (lo < hi) {
        unsigned mid = lo + ((hi - lo) >> 1);
        int c = 0;
        #pragma unroll
        for (int i = 0; i < 16; i++) c += (ue[i] <= mid) ? 1 : 0;
        int total = block_sum_i(c, sbi, tid);
        if (total >= KTH + 1) hi = mid; else lo = mid + 1;
    }
    const float thr = s2f(lo);

    if (BUILD) {
        if (tid == 0) scnt = 0;
        __syncthreads();
        #pragma unroll
        for (int i = 0; i < 16; i++) {
            if (fabsf(fe[i] - thr) <= EPSB) {
                int p = atomicAdd(&scnt, 1);
                if (p < MAXBAND) list[b * MAXBAND + p] = tid + i * 256;
            }
        }
        __syncthreads();
        if (tid == 0) counts[b] = scnt < MAXBAND ? scnt : MAXBAND;
    } else {
        float m = -INFINITY;
        #pragma unroll
        for (int i = 0; i < 16; i++) if (fe[i] < thr) m = fmaxf(m, fe[i]);
        m = block_max_f(m, sbf, tid);
        float s = 0.f;
        #pragma unroll
        for (int i = 0; i < 16; i++) if (fe[i] < thr) s += expf(fe[i] - m);
        s = block_sum_f(s, sbf, tid);
        const float inv = 1.0f / s;
        #pragma unroll
        for (int i = 0; i < 16; i++)
            beta[(long)b * T_ + tid + i * 256] = (fe[i] < thr) ? expf(fe[i] - m) * inv : 0.0f;
    }
}

// ---------- phase 2.5: exact fp32 recompute of band rows, RB rows share one W1 stream ----------
__global__ __launch_bounds__(256) void k_refine(const float* __restrict__ x,
        const float* __restrict__ W1, const float* __restrict__ b1,
        const float* __restrict__ W2, const float* __restrict__ b2,
        const int* __restrict__ counts, const int* __restrict__ list,
        float* __restrict__ e) {
    const int b   = blockIdx.y;
    const int blk = blockIdx.x;            // 0..15
    const int cnt = counts[b];
    const int tid = threadIdx.x;
    __shared__ float xs[RB][D_];           // 16 KB
    __shared__ float sbf[4];

    for (int g = blk * RB; g < cnt; g += 16 * RB) {
        const int nr = min(RB, cnt - g);
        for (int j = 0; j < nr; j++) {
            const int t = list[b * MAXBAND + g + j];
            *(float4*)&xs[j][tid * 4] =
                *(const float4*)&x[((long)b * T_ + t) * D_ + tid * 4];
        }
        __syncthreads();

        float a0 = 0.f, a1 = 0.f, a2 = 0.f, a3 = 0.f;
        for (int k0 = 0; k0 < D_; k0 += 4) {
            const float w0 = W1[(long)(k0 + 0) * H_ + tid];
            const float w1v = W1[(long)(k0 + 1) * H_ + tid];
            const float w2q = W1[(long)(k0 + 2) * H_ + tid];
            const float w3 = W1[(long)(k0 + 3) * H_ + tid];
            {
                float4 xv = *(const float4*)&xs[0][k0];
                a0 = fmaf(xv.x, w0, a0); a0 = fmaf(xv.y, w1v, a0);
                a0 = fmaf(xv.z, w2q, a0); a0 = fmaf(xv.w, w3, a0);
            }
            {
                float4 xv = *(const float4*)&xs[1][k0];
                a1 = fmaf(xv.x, w0, a1); a1 = fmaf(xv.y, w1v, a1);
                a1 = fmaf(xv.z, w2q, a1); a1 = fmaf(xv.w, w3, a1);
            }
            {
                float4 xv = *(const float4*)&xs[2][k0];
                a2 = fmaf(xv.x, w0, a2); a2 = fmaf(xv.y, w1v, a2);
                a2 = fmaf(xv.z, w2q, a2); a2 = fmaf(xv.w, w3, a2);
            }
            {
                float4 xv = *(const float4*)&xs[3][k0];
                a3 = fmaf(xv.x, w0, a3); a3 = fmaf(xv.y, w1v, a3);
                a3 = fmaf(xv.z, w2q, a3); a3 = fmaf(xv.w, w3, a3);
            }
        }

        float aj[RB] = {a0, a1, a2, a3};
        for (int j = 0; j < nr; j++) {
            float v = tanhf(aj[j] + b1[tid]) * W2[tid];
            float tot = block_sum_f(v, sbf, tid);
            if (tid == 0) {
                const int t = list[b * MAXBAND + g + j];
                e[(long)b * T_ + t] = tot + b2[0];
            }
            __syncthreads();
        }
        __syncthreads();
    }
}

// ---------- phase 3: partial[b][c][d] = sum_{t in chunk} beta*x ----------
__global__ __launch_bounds__(256) void k_pv(const float* __restrict__ x,
                                            const float* __restrict__ beta,
                                            float* __restrict__ partial) {
    const int c = blockIdx.x, b = blockIdx.y, tid = threadIdx.x;
    __shared__ float sBeta[TC];
    sBeta[tid] = beta[(long)b * T_ + c * TC + tid];
    __syncthreads();
    float4 acc = {0.f, 0.f, 0.f, 0.f};
    const float* xb = x + ((long)b * T_ + (long)c * TC) * D_ + tid * 4;
    for (int t = 0; t < TC; t++) {
        float w = sBeta[t];
        if (w != 0.0f) {
            float4 v = *reinterpret_cast<const float4*>(xb + (long)t * D_);
            acc.x = fmaf(w, v.x, acc.x);
            acc.y = fmaf(w, v.y, acc.y);
            acc.z = fmaf(w, v.z, acc.z);
            acc.w = fmaf(w, v.w, acc.w);
        }
    }
    *reinterpret_cast<float4*>(&partial[(((long)b * NC) + c) * D_ + tid * 4]) = acc;
}

// ---------- phase 4 ----------
__global__ __launch_bounds__(256) void k_red(const float* __restrict__ partial,
                                             float* __restrict__ out) {
    const int b = blockIdx.x, tid = threadIdx.x;
    float4 acc = {0.f, 0.f, 0.f, 0.f};
    #pragma unroll
    for (int c = 0; c < NC; c++) {
        float4 v = *reinterpret_cast<const float4*>(&partial[(((long)b * NC) + c) * D_ + tid * 4]);
        acc.x += v.x; acc.y += v.y; acc.z += v.z; acc.w += v.w;
    }
    *reinterpret_cast<float4*>(&out[(long)b * D_ + tid * 4]) = acc;
}

extern "C" void kernel_launch(void* const* d_in, const int* in_sizes, int n_in,
                              void* d_out, int out_size, void* d_ws, size_t ws_size,
                              hipStream_t stream) {
    const float* x  = (const float*)d_in[0];
    const float* W1 = (const float*)d_in[1];
    const float* b1 = (const float*)d_in[2];
    const float* W2 = (const float*)d_in[3];
    const float* b2 = (const float*)d_in[4];
    float* out = (float*)d_out;

    char* ws = (char*)d_ws;
    float* e       = (float*)ws;  ws += (size_t)B_ * T_ * 4;
    float* beta    = (float*)ws;  ws += (size_t)B_ * T_ * 4;
    float* partial = (float*)ws;  ws += (size_t)B_ * NC * D_ * 4;
    ushort* Whi    = (ushort*)ws; ws += (size_t)H_ * D_ * 2;
    int* counts    = (int*)ws;    ws += 128;
    int* list      = (int*)ws;

    k_w1t<<<dim3(D_ / 32, H_ / 32), 256, 0, stream>>>(W1, Whi);
    k_e_mfma<<<(B_ * T_) / BM, 512, 0, stream>>>(x, Whi, b1, W2, b2, e);
    k_thresh<1><<<B_, 256, 0, stream>>>(e, nullptr, counts, list);
    k_refine<<<dim3(16, B_), 256, 0, stream>>>(x, W1, b1, W2, b2, counts, list, e);
    k_thresh<0><<<B_, 256, 0, stream>>>(e, beta, counts, list);
    k_pv<<<dim3(NC, B_), 256, 0, stream>>>(x, beta, partial);
    k_red<<<B_, 256, 0, stream>>>(partial, out);
}

// Round 6
// 319.179 us; speedup vs baseline: 1.7761x; 1.1069x over previous
//
#include <hip/hip_runtime.h>
#include <hip/hip_bf16.h>
#include <math.h>

#define B_   32
#define T_   4096
#define D_   1024
#define H_   256
#define KTH  2048           // threshold_index = int(T*0.5)
#define SC   32             // pv chunks per batch
#define BM   128
#define BKE  32
#define NTE  (D_/BKE)       // 32 k-steps
#define ABUF (BM*BKE)       // ushorts per A buf (8 KB)
#define BBUF (H_*BKE)       // ushorts per B buf (16 KB)
#define EPSB 4.0e-3f        // refinement band half-width (~8 sigma of bf16 e-error)
#define MAXBAND 256
#define RB   4              // refine rows per block-group

typedef __attribute__((ext_vector_type(8))) short short8;
typedef __attribute__((ext_vector_type(4))) float f32x4;

#define FENCE4() asm volatile("s_waitcnt vmcnt(4) lgkmcnt(0)" ::: "memory")
#define FENCE0() asm volatile("s_waitcnt vmcnt(0) lgkmcnt(0)" ::: "memory")
#define BARRIER() __builtin_amdgcn_s_barrier()
#define SCHED()  __builtin_amdgcn_sched_barrier(0)
#define GLL(src, dst) __builtin_amdgcn_global_load_lds( \
    (const __attribute__((address_space(1))) unsigned int*)(src), \
    (__attribute__((address_space(3))) unsigned int*)(dst), 16, 0, 0)

// ---------- helpers ----------
__device__ inline unsigned f2s(float f) {
    unsigned u = __float_as_uint(f);
    return (u & 0x80000000u) ? ~u : (u | 0x80000000u);
}
__device__ inline float s2f(unsigned s) {
    unsigned x = (s & 0x80000000u) ? (s & 0x7fffffffu) : ~s;
    return __uint_as_float(x);
}
__device__ inline unsigned f2bf_rne(float f) {      // round-to-nearest-even bf16
    unsigned u = __float_as_uint(f);
    return (u + 0x7FFFu + ((u >> 16) & 1u)) >> 16;
}
__device__ inline unsigned pk2(float a, float b) {
    return f2bf_rne(a) | (f2bf_rne(b) << 16);
}
__device__ inline int block_sum_i(int v, int* sb, int tid) {
    #pragma unroll
    for (int o = 32; o; o >>= 1) v += __shfl_down(v, o);
    __syncthreads();
    if ((tid & 63) == 0) sb[tid >> 6] = v;
    __syncthreads();
    return sb[0] + sb[1] + sb[2] + sb[3];
}
__device__ inline float block_max_f(float v, float* sb, int tid) {
    #pragma unroll
    for (int o = 32; o; o >>= 1) v = fmaxf(v, __shfl_down(v, o));
    __syncthreads();
    if ((tid & 63) == 0) sb[tid >> 6] = v;
    __syncthreads();
    return fmaxf(fmaxf(sb[0], sb[1]), fmaxf(sb[2], sb[3]));
}
__device__ inline float block_sum_f(float v, float* sb, int tid) {
    #pragma unroll
    for (int o = 32; o; o >>= 1) v += __shfl_down(v, o);
    __syncthreads();
    if ((tid & 63) == 0) sb[tid >> 6] = v;
    __syncthreads();
    return sb[0] + sb[1] + sb[2] + sb[3];
}

// ---------- W1 [K][N] fp32 -> W1T bf16(RNE) [N][K] ----------
__global__ __launch_bounds__(256) void k_w1t(const float* __restrict__ W1,
                                             ushort* __restrict__ Whi) {
    __shared__ float tile[32][33];
    const int kb = blockIdx.x * 32, nb = blockIdx.y * 32;
    const int tx = threadIdx.x & 31, ty = threadIdx.x >> 5;   // ty 0..7
    #pragma unroll
    for (int i = 0; i < 4; i++)
        tile[ty + 8*i][tx] = W1[(long)(kb + ty + 8*i) * H_ + nb + tx];
    __syncthreads();
    #pragma unroll
    for (int i = 0; i < 4; i++) {
        long o = (long)(nb + ty + 8*i) * D_ + kb + tx;
        Whi[o] = (ushort)f2bf_rne(tile[tx][ty + 8*i]);
    }
}

// ---------- phase 1: counted-vmcnt depth-2 pipelined MFMA GEMM -> e ----------
// 512 thr = 8 waves (2m x 4n), block tile 128x256, BK=32.
// B: global_load_lds width-16 into 3 rotating bufs. A: reg-staged 2 tiles deep,
// cvt+ds_write late into 2 rotating bufs. One raw s_barrier per k-step with
// s_waitcnt vmcnt(4) (never 0 in the loop). LDS fragment-major layout:
// [slab=row>>4][kchunk][row&15][8] -> every frag ds_read_b128 = base+lane*16.
__global__ __launch_bounds__(512, 4) void k_e_mfma(
    const float* __restrict__ x,
    const ushort* __restrict__ Whi,
    const float* __restrict__ b1, const float* __restrict__ W2,
    const float* __restrict__ b2, float* __restrict__ e_out)
{
    __shared__ ushort sA[2][ABUF];   // 8 KB per buf
    __shared__ ushort sB[3][BBUF];   // 16 KB per buf
    __shared__ float  sRed[4][BM];

    const int tid  = threadIdx.x;
    const int lane = tid & 63;
    const int wv   = tid >> 6;
    const int wm   = wv >> 2, wn = wv & 3;
    const int l15  = lane & 15, lg = lane >> 4;
    const long row0 = (long)blockIdx.x * BM;

    // A staging: thread -> (row=tid>>2, kchunk=tid&3), 8 fp32 (32B)
    const int ar = tid >> 2, aj = tid & 3;
    const float* aga = x + (row0 + ar) * (long)D_ + aj * 8;
    const int awo = (ar >> 4) * 512 + aj * 128 + (ar & 15) * 8;

    // B staging: two 16B chunks/thread; chunk c: n=(c>>6)*16+(c&15), kc=(c>>4)&3
    const int c0 = tid, c1 = tid + 512;
    const int bn0 = (c0 >> 6) * 16 + (c0 & 15), bk0 = (c0 >> 4) & 3;
    const int bn1 = (c1 >> 6) * 16 + (c1 & 15), bk1 = (c1 >> 4) & 3;
    const ushort* bga0 = Whi + (long)bn0 * D_ + bk0 * 8;
    const ushort* bga1 = Whi + (long)bn1 * D_ + bk1 * 8;
    const int bdst0 = c0 * 8, bdst1 = c1 * 8;

    int aoff[4], boff[4];
    #pragma unroll
    for (int fm = 0; fm < 4; fm++)
        aoff[fm] = (wm * 4 + fm) * 512 + lg * 128 + l15 * 8;
    #pragma unroll
    for (int fn = 0; fn < 4; fn++)
        boff[fn] = (wn * 4 + fn) * 512 + lg * 128 + l15 * 8;

    f32x4 acc[4][4];
    #pragma unroll
    for (int i = 0; i < 4; i++)
        #pragma unroll
        for (int j = 0; j < 4; j++) acc[i][j] = (f32x4){0.f, 0.f, 0.f, 0.f};

    ushort* sBb = (ushort*)sB;
    auto stageB = [&](int ko, int bi) {
        GLL(bga0 + ko, sBb + bi * BBUF + bdst0);
        GLL(bga1 + ko, sBb + bi * BBUF + bdst1);
    };
    auto writeA = [&](ushort* dst, const float4& a0, const float4& a1) {
        uint4 ap = make_uint4(pk2(a0.x, a0.y), pk2(a0.z, a0.w),
                              pk2(a1.x, a1.y), pk2(a1.z, a1.w));
        *(uint4*)&dst[awo] = ap;
    };
    auto compute = [&](const ushort* sa, const ushort* sb) {
        short8 bfr[4];
        #pragma unroll
        for (int fn = 0; fn < 4; fn++)
            bfr[fn] = *(const short8*)&sb[boff[fn]];
        #pragma unroll
        for (int fm = 0; fm < 4; fm++) {
            short8 afr = *(const short8*)&sa[aoff[fm]];
            #pragma unroll
            for (int fn = 0; fn < 4; fn++)
                acc[fm][fn] = __builtin_amdgcn_mfma_f32_16x16x32_bf16(afr, bfr[fn], acc[fm][fn], 0, 0, 0);
        }
    };

    // prologue: issue tiles 0 and 1; ds_write A(0)
    float4 rA0a = *(const float4*)(aga);
    float4 rA0b = *(const float4*)(aga + 4);
    stageB(0, 0);
    float4 rA1a = *(const float4*)(aga + BKE);
    float4 rA1b = *(const float4*)(aga + BKE + 4);
    stageB(BKE, 1);
    writeA(sA[0], rA0a, rA0b);

    for (int t = 0; t < NTE - 2; t += 2) {
        // even sub-iter t: read sA[0], sB[t%3]; issue A(t+2)->R0, B(t+2); write A(t+1) from R1
        FENCE4(); BARRIER(); SCHED();
        {
            const int ko = (t + 2) * BKE;
            rA0a = *(const float4*)(aga + ko);
            rA0b = *(const float4*)(aga + ko + 4);
            stageB(ko, (t + 2) % 3);
            compute(sA[0], sBb + (t % 3) * BBUF);
            writeA(sA[1], rA1a, rA1b);
        }
        // odd sub-iter t+1: read sA[1], sB[(t+1)%3]; issue A(t+3)->R1, B(t+3); write A(t+2) from R0
        FENCE4(); BARRIER(); SCHED();
        {
            const int ko = (t + 3) * BKE;
            rA1a = *(const float4*)(aga + ko);
            rA1b = *(const float4*)(aga + ko + 4);
            stageB(ko, (t + 3) % 3);
            compute(sA[1], sBb + ((t + 1) % 3) * BBUF);
            writeA(sA[0], rA0a, rA0b);
        }
    }
    // t = NTE-2 (=30): no more issues; write A(31) from R1
    FENCE4(); BARRIER(); SCHED();
    compute(sA[0], sBb + ((NTE - 2) % 3) * BBUF);
    writeA(sA[1], rA1a, rA1b);
    // t = NTE-1 (=31): final drain
    FENCE0(); BARRIER(); SCHED();
    compute(sA[1], sBb + ((NTE - 1) % 3) * BBUF);

    // epilogue: e partial = sum_j tanh(G+b1[j])*W2[j]; D frag: col=l15, row=lg*4+r
    float b1v[4], w2v[4];
    #pragma unroll
    for (int fn = 0; fn < 4; fn++) {
        int j = wn * 64 + fn * 16 + l15;
        b1v[fn] = b1[j]; w2v[fn] = W2[j];
    }
    #pragma unroll
    for (int fm = 0; fm < 4; fm++) {
        #pragma unroll
        for (int r = 0; r < 4; r++) {
            float s = 0.f;
            #pragma unroll
            for (int fn = 0; fn < 4; fn++)
                s += tanhf(acc[fm][fn][r] + b1v[fn]) * w2v[fn];
            s += __shfl_xor(s, 1); s += __shfl_xor(s, 2);
            s += __shfl_xor(s, 4); s += __shfl_xor(s, 8);
            if (l15 == 0) sRed[wn][wm * 64 + fm * 16 + lg * 4 + r] = s;
        }
    }
    __syncthreads();
    if (tid < BM)
        e_out[row0 + tid] = sRed[0][tid] + sRed[1][tid] + sRed[2][tid] + sRed[3][tid] + b2[0];
}

// ---------- phase 2: rank threshold; BUILD=1 -> band list, BUILD=0 -> survivor list ----------
// thread handles 16 CONSECUTIVE t (t = tid*16+i) so compaction is t-ordered.
template<int BUILD>
__global__ __launch_bounds__(256) void k_thresh(const float* __restrict__ e,
                                                int* __restrict__ counts,
                                                int* __restrict__ list,
                                                int* __restrict__ sidx,
                                                float* __restrict__ sval,
                                                int* __restrict__ scount) {
    __shared__ int   sbi[4];
    __shared__ float sbf[4];
    __shared__ int   wsum[4];
    __shared__ int   scnt;
    const int b = blockIdx.x, tid = threadIdx.x;
    const int lane = tid & 63, wid = tid >> 6;
    const float* eb = e + (long)b * T_;
    const int t0 = tid * 16;

    float fe[16]; unsigned ue[16];
    #pragma unroll
    for (int i = 0; i < 16; i += 4) {
        float4 v = *(const float4*)(eb + t0 + i);
        fe[i] = v.x; fe[i+1] = v.y; fe[i+2] = v.z; fe[i+3] = v.w;
    }
    #pragma unroll
    for (int i = 0; i < 16; i++) ue[i] = f2s(fe[i]);

    unsigned lo = 0u, hi = 0xFFFFFFFFu;
    while (lo < hi) {
        unsigned mid = lo + ((hi - lo) >> 1);
        int c = 0;
        #pragma unroll
        for (int i = 0; i < 16; i++) c += (ue[i] <= mid) ? 1 : 0;
        int total = block_sum_i(c, sbi, tid);
        if (total >= KTH + 1) hi = mid; else lo = mid + 1;
    }
    const float thr = s2f(lo);

    if (BUILD) {
        if (tid == 0) scnt = 0;
        __syncthreads();
        #pragma unroll
        for (int i = 0; i < 16; i++) {
            if (fabsf(fe[i] - thr) <= EPSB) {
                int p = atomicAdd(&scnt, 1);
                if (p < MAXBAND) list[b * MAXBAND + p] = t0 + i;
            }
        }
        __syncthreads();
        if (tid == 0) counts[b] = scnt < MAXBAND ? scnt : MAXBAND;
    } else {
        float m = -INFINITY;
        #pragma unroll
        for (int i = 0; i < 16; i++) if (fe[i] < thr) m = fmaxf(m, fe[i]);
        m = block_max_f(m, sbf, tid);
        float s = 0.f;
        #pragma unroll
        for (int i = 0; i < 16; i++) if (fe[i] < thr) s += expf(fe[i] - m);
        s = block_sum_f(s, sbf, tid);
        const float inv = 1.0f / s;

        // deterministic t-ordered compaction: block exclusive scan of counts
        int c = 0;
        #pragma unroll
        for (int i = 0; i < 16; i++) c += (fe[i] < thr) ? 1 : 0;
        int p = c;
        #pragma unroll
        for (int o = 1; o < 64; o <<= 1) {
            int y = __shfl_up(p, o);
            if (lane >= o) p += y;
        }
        if (lane == 63) wsum[wid] = p;          // wave total
        __syncthreads();
        int base = 0;
        #pragma unroll
        for (int w = 0; w < 4; w++) base += (w < wid) ? wsum[w] : 0;
        int pos = base + p - c;                 // exclusive prefix
        #pragma unroll
        for (int i = 0; i < 16; i++) {
            if (fe[i] < thr) {
                sidx[(long)b * T_ + pos] = t0 + i;
                sval[(long)b * T_ + pos] = expf(fe[i] - m) * inv;
                pos++;
            }
        }
        if (tid == 0) scount[b] = wsum[0] + wsum[1] + wsum[2] + wsum[3];
    }
}

// ---------- phase 2.5: exact fp32 recompute of band rows, RB rows share one W1 stream ----------
__global__ __launch_bounds__(256) void k_refine(const float* __restrict__ x,
        const float* __restrict__ W1, const float* __restrict__ b1,
        const float* __restrict__ W2, const float* __restrict__ b2,
        const int* __restrict__ counts, const int* __restrict__ list,
        float* __restrict__ e) {
    const int b   = blockIdx.y;
    const int blk = blockIdx.x;            // 0..15
    const int cnt = counts[b];
    const int tid = threadIdx.x;
    __shared__ float xs[RB][D_];           // 16 KB
    __shared__ float sbf[4];

    for (int g = blk * RB; g < cnt; g += 16 * RB) {
        const int nr = min(RB, cnt - g);
        for (int j = 0; j < nr; j++) {
            const int t = list[b * MAXBAND + g + j];
            *(float4*)&xs[j][tid * 4] =
                *(const float4*)&x[((long)b * T_ + t) * D_ + tid * 4];
        }
        __syncthreads();

        float a0 = 0.f, a1 = 0.f, a2 = 0.f, a3 = 0.f;
        for (int k0 = 0; k0 < D_; k0 += 4) {
            const float w0 = W1[(long)(k0 + 0) * H_ + tid];
            const float w1v = W1[(long)(k0 + 1) * H_ + tid];
            const float w2q = W1[(long)(k0 + 2) * H_ + tid];
            const float w3 = W1[(long)(k0 + 3) * H_ + tid];
            {
                float4 xv = *(const float4*)&xs[0][k0];
                a0 = fmaf(xv.x, w0, a0); a0 = fmaf(xv.y, w1v, a0);
                a0 = fmaf(xv.z, w2q, a0); a0 = fmaf(xv.w, w3, a0);
            }
            {
                float4 xv = *(const float4*)&xs[1][k0];
                a1 = fmaf(xv.x, w0, a1); a1 = fmaf(xv.y, w1v, a1);
                a1 = fmaf(xv.z, w2q, a1); a1 = fmaf(xv.w, w3, a1);
            }
            {
                float4 xv = *(const float4*)&xs[2][k0];
                a2 = fmaf(xv.x, w0, a2); a2 = fmaf(xv.y, w1v, a2);
                a2 = fmaf(xv.z, w2q, a2); a2 = fmaf(xv.w, w3, a2);
            }
            {
                float4 xv = *(const float4*)&xs[3][k0];
                a3 = fmaf(xv.x, w0, a3); a3 = fmaf(xv.y, w1v, a3);
                a3 = fmaf(xv.z, w2q, a3); a3 = fmaf(xv.w, w3, a3);
            }
        }

        float aj[RB] = {a0, a1, a2, a3};
        for (int j = 0; j < nr; j++) {
            float v = tanhf(aj[j] + b1[tid]) * W2[tid];
            float tot = block_sum_f(v, sbf, tid);
            if (tid == 0) {
                const int t = list[b * MAXBAND + g + j];
                e[(long)b * T_ + t] = tot + b2[0];
            }
            __syncthreads();
        }
        __syncthreads();
    }
}

// ---------- phase 3: dense survivor-list PV: partial[b][c][d] ----------
__global__ __launch_bounds__(256) void k_pv(const float* __restrict__ x,
                                            const int* __restrict__ sidx,
                                            const float* __restrict__ sval,
                                            const int* __restrict__ scount,
                                            float* __restrict__ partial) {
    const int c = blockIdx.x, b = blockIdx.y, tid = threadIdx.x;
    const int cnt = scount[b];
    const int len = (cnt + SC - 1) / SC;
    const int k0 = c * len;
    const int nl = min(len, cnt - k0);
    __shared__ int   si[96];
    __shared__ float sv[96];
    if (tid < nl) {
        si[tid] = sidx[(long)b * T_ + k0 + tid];
        sv[tid] = sval[(long)b * T_ + k0 + tid];
    }
    __syncthreads();

    float4 acc = {0.f, 0.f, 0.f, 0.f};
    const float* xb = x + (long)b * T_ * D_ + tid * 4;
    for (int k = 0; k < nl; k++) {
        const float w = sv[k];
        float4 v = *(const float4*)(xb + (long)si[k] * D_);
        acc.x = fmaf(w, v.x, acc.x);
        acc.y = fmaf(w, v.y, acc.y);
        acc.z = fmaf(w, v.z, acc.z);
        acc.w = fmaf(w, v.w, acc.w);
    }
    *(float4*)&partial[(((long)b * SC) + c) * D_ + tid * 4] = acc;
}

// ---------- phase 4 ----------
__global__ __launch_bounds__(256) void k_red(const float* __restrict__ partial,
                                             float* __restrict__ out) {
    const int b = blockIdx.x, tid = threadIdx.x;
    float4 acc = {0.f, 0.f, 0.f, 0.f};
    #pragma unroll
    for (int c = 0; c < SC; c++) {
        float4 v = *(const float4*)&partial[(((long)b * SC) + c) * D_ + tid * 4];
        acc.x += v.x; acc.y += v.y; acc.z += v.z; acc.w += v.w;
    }
    *(float4*)&out[(long)b * D_ + tid * 4] = acc;
}

extern "C" void kernel_launch(void* const* d_in, const int* in_sizes, int n_in,
                              void* d_out, int out_size, void* d_ws, size_t ws_size,
                              hipStream_t stream) {
    const float* x  = (const float*)d_in[0];
    const float* W1 = (const float*)d_in[1];
    const float* b1 = (const float*)d_in[2];
    const float* W2 = (const float*)d_in[3];
    const float* b2 = (const float*)d_in[4];
    float* out = (float*)d_out;

    char* ws = (char*)d_ws;
    float* e       = (float*)ws;  ws += (size_t)B_ * T_ * 4;
    int*   sidx    = (int*)ws;    ws += (size_t)B_ * T_ * 4;
    float* sval    = (float*)ws;  ws += (size_t)B_ * T_ * 4;
    float* partial = (float*)ws;  ws += (size_t)B_ * SC * D_ * 4;
    ushort* Whi    = (ushort*)ws; ws += (size_t)H_ * D_ * 2;
    int* counts    = (int*)ws;    ws += 128;
    int* scountp   = (int*)ws;    ws += 128;
    int* list      = (int*)ws;

    k_w1t<<<dim3(D_ / 32, H_ / 32), 256, 0, stream>>>(W1, Whi);
    k_e_mfma<<<(B_ * T_) / BM, 512, 0, stream>>>(x, Whi, b1, W2, b2, e);
    k_thresh<1><<<B_, 256, 0, stream>>>(e, counts, list, sidx, sval, scountp);
    k_refine<<<dim3(16, B_), 256, 0, stream>>>(x, W1, b1, W2, b2, counts, list, e);
    k_thresh<0><<<B_, 256, 0, stream>>>(e, counts, list, sidx, sval, scountp);
    k_pv<<<dim3(SC, B_), 256, 0, stream>>>(x, sidx, sval, scountp, partial);
    k_red<<<B_, 256, 0, stream>>>(partial, out);
}